// Round 1
// baseline (1891.692 us; speedup 1.0000x reference)
//
#include <hip/hip_runtime.h>

typedef __attribute__((ext_vector_type(8))) short bf16x8;
typedef __attribute__((ext_vector_type(4))) float f32x4;

#define MFMA16(a, b, c) __builtin_amdgcn_mfma_f32_16x16x32_bf16(a, b, c, 0, 0, 0)

__device__ __forceinline__ unsigned short f2bf(float f) {
    unsigned int u = __float_as_uint(f);
    u += 0x7FFFu + ((u >> 16) & 1u);
    return (unsigned short)(u >> 16);
}
__device__ __forceinline__ float bf2f(unsigned short h) {
    return __uint_as_float(((unsigned int)h) << 16);
}

// ---------------- weight conversion: 6 tensors x [2,256,256] f32 -> bf16 ----
struct WPtrs { const float* p[6]; };

__global__ __launch_bounds__(256) void conv_w_kernel(WPtrs wp, unsigned short* dst) {
    int idx = blockIdx.x * 256 + threadIdx.x;      // 196608 threads, 4 elems each
    if (idx >= 196608) return;
    int t = idx >> 15;                              // 32768 quads per tensor
    int q = idx & 32767;
    float4 v = *(const float4*)(wp.p[t] + ((size_t)q << 2));
    ushort4 o;
    o.x = f2bf(v.x); o.y = f2bf(v.y); o.z = f2bf(v.z); o.w = f2bf(v.w);
    *(ushort4*)(dst + ((size_t)t << 17) + ((size_t)q << 2)) = o;
}

// ---------------- feats f32 -> bf16 (same layout) ---------------------------
__global__ __launch_bounds__(256) void conv_in_kernel(const float* __restrict__ src,
                                                      unsigned short* __restrict__ dst, int n4) {
    for (int i = blockIdx.x * 256 + threadIdx.x; i < n4; i += gridDim.x * 256) {
        float4 v = *(const float4*)(src + 4 * (size_t)i);
        ushort4 o;
        o.x = f2bf(v.x); o.y = f2bf(v.y); o.z = f2bf(v.z); o.w = f2bf(v.w);
        *(ushort4*)(dst + 4 * (size_t)i) = o;
    }
}

// ---------------- in-place batched 96x96 transpose (last two dims) ----------
__global__ __launch_bounds__(256) void transpose_ip(unsigned short* __restrict__ x) {
    __shared__ unsigned short t[96 * 98];
    const size_t base = (size_t)blockIdx.x * 9216;
    for (int i = threadIdx.x; i < 2304; i += 256) {
        int r = i / 24, c4 = (i % 24) * 4;
        ushort4 v = *(const ushort4*)(x + base + r * 96 + c4);
        t[r * 98 + c4 + 0] = v.x; t[r * 98 + c4 + 1] = v.y;
        t[r * 98 + c4 + 2] = v.z; t[r * 98 + c4 + 3] = v.w;
    }
    __syncthreads();
    for (int i = threadIdx.x; i < 2304; i += 256) {
        int r = i / 24, c4 = (i % 24) * 4;
        ushort4 o;
        o.x = t[(c4 + 0) * 98 + r]; o.y = t[(c4 + 1) * 98 + r];
        o.z = t[(c4 + 2) * 98 + r]; o.w = t[(c4 + 3) * 98 + r];
        *(ushort4*)(x + base + r * 96 + c4) = o;
    }
}

// ---------------- final: transpose + bf16->f32 into d_out -------------------
__global__ __launch_bounds__(256) void final_t(const unsigned short* __restrict__ x,
                                               float* __restrict__ out) {
    __shared__ unsigned short t[96 * 98];
    const size_t base = (size_t)blockIdx.x * 9216;
    for (int i = threadIdx.x; i < 2304; i += 256) {
        int r = i / 24, c4 = (i % 24) * 4;
        ushort4 v = *(const ushort4*)(x + base + r * 96 + c4);
        t[r * 98 + c4 + 0] = v.x; t[r * 98 + c4 + 1] = v.y;
        t[r * 98 + c4 + 2] = v.z; t[r * 98 + c4 + 3] = v.w;
    }
    __syncthreads();
    for (int i = threadIdx.x; i < 2304; i += 256) {
        int r = i / 24, c4 = (i % 24) * 4;
        float4 f;
        f.x = bf2f(t[(c4 + 0) * 98 + r]); f.y = bf2f(t[(c4 + 1) * 98 + r]);
        f.z = bf2f(t[(c4 + 2) * 98 + r]); f.w = bf2f(t[(c4 + 3) * 98 + r]);
        *(float4*)(out + base + r * 96 + c4) = f;
    }
}

// ---------------- masks output ----------------------------------------------
__global__ __launch_bounds__(256) void masks_kernel(const int* __restrict__ nr,
                                                    const int* __restrict__ nc,
                                                    float* __restrict__ out) {
    int i = blockIdx.x * 256 + threadIdx.x;   // 147456 total
    if (i >= 147456) return;
    int b = i / 9216, rem = i % 9216, r = rem / 96, c = rem % 96;
    out[i] = (r < nr[b] && c < nc[b]) ? 1.0f : 0.0f;
}

// ---------------- fused per-sequence self-attention (in-place) --------------
// x viewed as [16][256][96][96]; sequence = (b, s) over slab x[b, :, s, :].
// LDS plan (bytes):
//   xs  [96][264] bf16  @0       (x transposed: [n][c], c-contiguous)
//   Kt  [96][72]  bf16  @50688   ([n][d], d-contiguous)
//   Qt  [96][72]  bf16  @64512
//   Vm  [64][104] bf16  @78336   ([d][m], m-contiguous)
//   Lg  [96][100] f32   @91648   (logits TRANSPOSED: [m][n])
//   Pm  [96][104] bf16  @130048  ([n][m], m-contiguous)   total 150016
#define XS_S 264
#define KT_S 72
#define VM_S 104
#define LG_S 100
#define P_S  104

__global__ __launch_bounds__(384, 1) void sa_kernel(
    unsigned short* __restrict__ x,
    const unsigned short* __restrict__ Wk, const unsigned short* __restrict__ Wq,
    const unsigned short* __restrict__ Wv,
    const float* __restrict__ bk, const float* __restrict__ bq, const float* __restrict__ bv,
    const int* __restrict__ lim_s, const int* __restrict__ lim_m) {
    extern __shared__ char smem[];
    unsigned short* xs = (unsigned short*)smem;
    unsigned short* Kt = (unsigned short*)(smem + 50688);
    unsigned short* Qt = (unsigned short*)(smem + 64512);
    unsigned short* Vm = (unsigned short*)(smem + 78336);
    float*          Lg = (float*)(smem + 91648);
    unsigned short* Pm = (unsigned short*)(smem + 130048);

    const int b = blockIdx.x / 96;
    const int s = blockIdx.x % 96;
    if (s >= lim_s[b]) return;                  // fully-masked: out = x (in-place no-op)
    const int mlim = lim_m[b];

    unsigned short* xg = x + (size_t)b * 2359296 + (size_t)s * 96;
    const int tid = threadIdx.x;

    // ---- stage x[b,:,s,:] -> xs[n][c] (transpose; rotated j to spread banks)
    {
        const int lc = tid / 12;                // 0..31
        const int ln = tid % 12;                // n-octet
        for (int it = 0; it < 8; ++it) {
            int c = it * 32 + lc;
            uint4 v = *(const uint4*)(xg + (size_t)c * 9216 + ln * 8);
            const unsigned short* pv = (const unsigned short*)&v;
#pragma unroll
            for (int j = 0; j < 8; ++j) {
                int jj = (j + ln) & 7;
                xs[(ln * 8 + jj) * XS_S + c] = pv[jj];
            }
        }
    }
    __syncthreads();

    const int wave = tid >> 6;                  // 0..5
    const int lane = tid & 63;
    const int lr = lane & 15;
    const int lk = lane >> 4;

    for (int h = 0; h < 4; ++h) {
        // ---- projections: wave = (proj p, row-half g); K=256 -------------
        {
            const int p = wave >> 1;
            const int g = wave & 1;
            const unsigned short* Wp = (p == 0) ? Wk : (p == 1) ? Wq : Wv;
            const float* bp = (p == 0) ? bk : (p == 1) ? bq : bv;
            f32x4 acc[2][6];
#pragma unroll
            for (int dt = 0; dt < 2; ++dt)
#pragma unroll
                for (int nt = 0; nt < 6; ++nt) acc[dt][nt] = (f32x4)0.0f;
            for (int k0 = 0; k0 < 256; k0 += 32) {
                bf16x8 bfr[6];
#pragma unroll
                for (int nt = 0; nt < 6; ++nt)
                    bfr[nt] = *(const bf16x8*)&xs[(nt * 16 + lr) * XS_S + k0 + lk * 8];
#pragma unroll
                for (int dt = 0; dt < 2; ++dt) {
                    bf16x8 afr = *(const bf16x8*)&Wp[(size_t)(h * 64 + g * 32 + dt * 16 + lr) * 256 + k0 + lk * 8];
#pragma unroll
                    for (int nt = 0; nt < 6; ++nt)
                        acc[dt][nt] = MFMA16(afr, bfr[nt], acc[dt][nt]);
                }
            }
#pragma unroll
            for (int dt = 0; dt < 2; ++dt) {
                const int dl = g * 32 + dt * 16 + lk * 4;
#pragma unroll
                for (int nt = 0; nt < 6; ++nt) {
                    const int n = nt * 16 + lr;
                    if (p == 2) {
#pragma unroll
                        for (int r2 = 0; r2 < 4; ++r2)
                            Vm[(dl + r2) * VM_S + n] = f2bf(acc[dt][nt][r2] + bp[h * 64 + dl + r2]);
                    } else {
                        ushort4 o;
                        o.x = f2bf(acc[dt][nt][0] + bp[h * 64 + dl + 0]);
                        o.y = f2bf(acc[dt][nt][1] + bp[h * 64 + dl + 1]);
                        o.z = f2bf(acc[dt][nt][2] + bp[h * 64 + dl + 2]);
                        o.w = f2bf(acc[dt][nt][3] + bp[h * 64 + dl + 3]);
                        *(ushort4*)((p == 0 ? Kt : Qt) + n * KT_S + dl) = o;
                    }
                }
            }
        }
        __syncthreads();

        // ---- logits: wave = m-tile; Lg[m][n] = scale * sum_d K[d,n]Q[d,m] --
        {
            const int mt = wave;
            if (mt * 16 < mlim) {
                f32x4 acc2[6];
#pragma unroll
                for (int nt = 0; nt < 6; ++nt) acc2[nt] = (f32x4)0.0f;
#pragma unroll
                for (int k0 = 0; k0 < 64; k0 += 32) {
                    bf16x8 qf = *(const bf16x8*)&Qt[(mt * 16 + lr) * KT_S + k0 + lk * 8];
#pragma unroll
                    for (int nt = 0; nt < 6; ++nt) {
                        bf16x8 kf = *(const bf16x8*)&Kt[(nt * 16 + lr) * KT_S + k0 + lk * 8];
                        acc2[nt] = MFMA16(kf, qf, acc2[nt]);
                    }
                }
#pragma unroll
                for (int nt = 0; nt < 6; ++nt)
#pragma unroll
                    for (int r2 = 0; r2 < 4; ++r2)
                        Lg[(mt * 16 + lr) * LG_S + nt * 16 + lk * 4 + r2] = acc2[nt][r2] * 0.125f;
            }
        }
        __syncthreads();

        // ---- masked softmax over m (one thread per query row n) -----------
        if (tid < 96) {
            const int n = tid;
            float mx = -3.0e38f;
            for (int m = 0; m < mlim; ++m) mx = fmaxf(mx, Lg[m * LG_S + n]);
            float ssum = 0.0f;
            for (int m = 0; m < mlim; ++m) {
                float e = __expf(Lg[m * LG_S + n] - mx);
                ssum += e;
                Lg[m * LG_S + n] = e;
            }
            const float inv = 1.0f / ssum;
            for (int m = 0; m < 96; ++m)
                Pm[n * P_S + m] = (m < mlim) ? f2bf(Lg[m * LG_S + n] * inv) : (unsigned short)0;
        }
        __syncthreads();

        // ---- PV + residual + in-place store: wave = n-tile ----------------
        {
            const int ntl = wave;
            f32x4 acc3[4];
#pragma unroll
            for (int dt = 0; dt < 4; ++dt) acc3[dt] = (f32x4)0.0f;
            const int mk = (mlim + 31) >> 5;
            for (int ki = 0; ki < mk; ++ki) {
                const int k0 = ki * 32;
                bf16x8 pf = *(const bf16x8*)&Pm[(ntl * 16 + lr) * P_S + k0 + lk * 8];
#pragma unroll
                for (int dt = 0; dt < 4; ++dt) {
                    bf16x8 vf = *(const bf16x8*)&Vm[(dt * 16 + lr) * VM_S + k0 + lk * 8];
                    acc3[dt] = MFMA16(vf, pf, acc3[dt]);
                }
            }
#pragma unroll
            for (int dt = 0; dt < 4; ++dt)
#pragma unroll
                for (int r2 = 0; r2 < 4; ++r2) {
                    const int dl = dt * 16 + lk * 4 + r2;
                    const int n = ntl * 16 + lr;
                    float val = acc3[dt][r2] + bf2f(xs[n * XS_S + h * 64 + dl]);
                    xg[(size_t)(h * 64 + dl) * 9216 + n] = f2bf(val);
                }
        }
        __syncthreads();
    }
}

// ---------------------------------------------------------------------------
extern "C" void kernel_launch(void* const* d_in, const int* in_sizes, int n_in,
                              void* d_out, int out_size, void* d_ws, size_t ws_size,
                              hipStream_t stream) {
    const float* feats    = (const float*)d_in[0];
    const int*   num_rows = (const int*)d_in[1];
    const int*   num_cols = (const int*)d_in[2];

    unsigned short* xbuf = (unsigned short*)d_ws;                       // 75497472 B
    unsigned short* wbuf = (unsigned short*)((char*)d_ws + 75497472);   // 1572864 B

    WPtrs wp;
    for (int t = 0; t < 6; ++t) wp.p[t] = (const float*)d_in[3 + 2 * t];

    (void)hipFuncSetAttribute((const void*)sa_kernel,
                              hipFuncAttributeMaxDynamicSharedMemorySize, 150016);

    conv_w_kernel<<<768, 256, 0, stream>>>(wp, wbuf);
    conv_in_kernel<<<2048, 256, 0, stream>>>(feats, xbuf, 9437184);

    for (int i = 0; i < 2; ++i) {
        for (int dir = 0; dir < 2; ++dir) {
            const int tb = dir * 3;   // col: tensors 0..2, row: tensors 3..5
            const unsigned short* Wk = wbuf + (size_t)(tb + 0) * 131072 + (size_t)i * 65536;
            const unsigned short* Wq = wbuf + (size_t)(tb + 1) * 131072 + (size_t)i * 65536;
            const unsigned short* Wv = wbuf + (size_t)(tb + 2) * 131072 + (size_t)i * 65536;
            const float* bk = (const float*)d_in[4 + 2 * (tb + 0)] + i * 256;
            const float* bq = (const float*)d_in[4 + 2 * (tb + 1)] + i * 256;
            const float* bv = (const float*)d_in[4 + 2 * (tb + 2)] + i * 256;
            const int* lim_s = (dir == 0) ? num_rows : num_cols;
            const int* lim_m = (dir == 0) ? num_cols : num_rows;
            sa_kernel<<<1536, 384, 150016, stream>>>(xbuf, Wk, Wq, Wv, bk, bq, bv, lim_s, lim_m);
            if (!(i == 1 && dir == 1))
                transpose_ip<<<4096, 256, 0, stream>>>(xbuf);
        }
    }

    final_t<<<4096, 256, 0, stream>>>(xbuf, (float*)d_out);
    masks_kernel<<<576, 256, 0, stream>>>(num_rows, num_cols, (float*)d_out + 37748736);
}

// Round 2
// 1328.017 us; speedup vs baseline: 1.4244x; 1.4244x over previous
//
#include <hip/hip_runtime.h>

typedef __attribute__((ext_vector_type(8))) short bf16x8;
typedef __attribute__((ext_vector_type(4))) float f32x4;

#define MFMA16(a, b, c) __builtin_amdgcn_mfma_f32_16x16x32_bf16(a, b, c, 0, 0, 0)

__device__ __forceinline__ unsigned short f2bf(float f) {
    unsigned int u = __float_as_uint(f);
    u += 0x7FFFu + ((u >> 16) & 1u);
    return (unsigned short)(u >> 16);
}
__device__ __forceinline__ float bf2f(unsigned short h) {
    return __uint_as_float(((unsigned int)h) << 16);
}

// ---------------- weight conversion: 6 tensors x [2,256,256] f32 -> bf16 ----
struct WPtrs { const float* p[6]; };

__global__ __launch_bounds__(256) void conv_w_kernel(WPtrs wp, unsigned short* dst) {
    int idx = blockIdx.x * 256 + threadIdx.x;
    if (idx >= 196608) return;
    int t = idx >> 15;
    int q = idx & 32767;
    float4 v = *(const float4*)(wp.p[t] + ((size_t)q << 2));
    ushort4 o;
    o.x = f2bf(v.x); o.y = f2bf(v.y); o.z = f2bf(v.z); o.w = f2bf(v.w);
    *(ushort4*)(dst + ((size_t)t << 17) + ((size_t)q << 2)) = o;
}

// ---------------- feats f32 -> bf16 -----------------------------------------
__global__ __launch_bounds__(256) void conv_in_kernel(const float* __restrict__ src,
                                                      unsigned short* __restrict__ dst, int n4) {
    for (int i = blockIdx.x * 256 + threadIdx.x; i < n4; i += gridDim.x * 256) {
        float4 v = *(const float4*)(src + 4 * (size_t)i);
        ushort4 o;
        o.x = f2bf(v.x); o.y = f2bf(v.y); o.z = f2bf(v.z); o.w = f2bf(v.w);
        *(ushort4*)(dst + 4 * (size_t)i) = o;
    }
}

// ---------------- in-place batched 96x96 transpose (last two dims) ----------
__global__ __launch_bounds__(256) void transpose_ip(unsigned short* __restrict__ x) {
    __shared__ unsigned short t[96 * 98];
    const size_t base = (size_t)blockIdx.x * 9216;
    for (int i = threadIdx.x; i < 2304; i += 256) {
        int r = i / 24, c4 = (i % 24) * 4;
        ushort4 v = *(const ushort4*)(x + base + r * 96 + c4);
        t[r * 98 + c4 + 0] = v.x; t[r * 98 + c4 + 1] = v.y;
        t[r * 98 + c4 + 2] = v.z; t[r * 98 + c4 + 3] = v.w;
    }
    __syncthreads();
    for (int i = threadIdx.x; i < 2304; i += 256) {
        int r = i / 24, c4 = (i % 24) * 4;
        ushort4 o;
        o.x = t[(c4 + 0) * 98 + r]; o.y = t[(c4 + 1) * 98 + r];
        o.z = t[(c4 + 2) * 98 + r]; o.w = t[(c4 + 3) * 98 + r];
        *(ushort4*)(x + base + r * 96 + c4) = o;
    }
}

// ---------------- final: transpose + bf16->f32 into d_out -------------------
__global__ __launch_bounds__(256) void final_t(const unsigned short* __restrict__ x,
                                               float* __restrict__ out) {
    __shared__ unsigned short t[96 * 98];
    const size_t base = (size_t)blockIdx.x * 9216;
    for (int i = threadIdx.x; i < 2304; i += 256) {
        int r = i / 24, c4 = (i % 24) * 4;
        ushort4 v = *(const ushort4*)(x + base + r * 96 + c4);
        t[r * 98 + c4 + 0] = v.x; t[r * 98 + c4 + 1] = v.y;
        t[r * 98 + c4 + 2] = v.z; t[r * 98 + c4 + 3] = v.w;
    }
    __syncthreads();
    for (int i = threadIdx.x; i < 2304; i += 256) {
        int r = i / 24, c4 = (i % 24) * 4;
        float4 f;
        f.x = bf2f(t[(c4 + 0) * 98 + r]); f.y = bf2f(t[(c4 + 1) * 98 + r]);
        f.z = bf2f(t[(c4 + 2) * 98 + r]); f.w = bf2f(t[(c4 + 3) * 98 + r]);
        *(float4*)(out + base + r * 96 + c4) = f;
    }
}

// ---------------- masks output ----------------------------------------------
__global__ __launch_bounds__(256) void masks_kernel(const int* __restrict__ nr,
                                                    const int* __restrict__ nc,
                                                    float* __restrict__ out) {
    int i = blockIdx.x * 256 + threadIdx.x;
    if (i >= 147456) return;
    int b = i / 9216, rem = i % 9216, r = rem / 96, c = rem % 96;
    out[i] = (r < nr[b] && c < nc[b]) ? 1.0f : 0.0f;
}

// ---------------- per-(sequence, head) fused self-attention -----------------
// x viewed as [16][256][96][96]; block = (b, s, h). src -> dst (not in place).
// LDS (bytes):
//   xt [96][40]  bf16 @0      (7680)   streamed x tile, [n][c-chunk]
//   Kt [96][72]  bf16 @7680   (13824)  [n][d]
//   Qt [96][72]  bf16 @21504  (13824)  [m][d]
//   Vm [64][104] bf16 @35328  (13312)  [d][m]
//   Pm [96][104] bf16 @48640  (19968)  [n][m]
//   OT [64][100] f32  @0      (25600)  overlays xt/Kt/Qt (dead by then)
#define XT_S 40
#define KT_S 72
#define VM_S 104
#define PM_S 104
#define OT_S 100

__global__ __launch_bounds__(384, 3) void sa2(
    const unsigned short* __restrict__ src, unsigned short* __restrict__ dst,
    const unsigned short* __restrict__ Wk, const unsigned short* __restrict__ Wq,
    const unsigned short* __restrict__ Wv,
    const float* __restrict__ bk, const float* __restrict__ bq, const float* __restrict__ bv,
    const int* __restrict__ lim_s, const int* __restrict__ lim_m) {
    extern __shared__ char smem[];
    unsigned short* xt = (unsigned short*)smem;
    unsigned short* Kt = (unsigned short*)(smem + 7680);
    unsigned short* Qt = (unsigned short*)(smem + 21504);
    unsigned short* Vm = (unsigned short*)(smem + 35328);
    unsigned short* Pm = (unsigned short*)(smem + 48640);
    float*          OT = (float*)smem;

    const int bid = blockIdx.x;
    const int h   = bid & 3;
    const int seq = bid >> 2;
    const int b = seq / 96, s = seq % 96;
    const int tid = threadIdx.x;

    const size_t slab = (size_t)b * 2359296 + (size_t)s * 96;
    const unsigned short* sg = src + slab;
    unsigned short* dg = dst + slab;

    if (s >= lim_s[b]) {
        // masked sequence: out = x (copy this head's 64 channel rows)
        for (int i = tid; i < 768; i += 384) {
            int c = h * 64 + i / 12, o8 = (i % 12) * 8;
            *(uint4*)(dg + (size_t)c * 9216 + o8) = *(const uint4*)(sg + (size_t)c * 9216 + o8);
        }
        return;
    }
    const int mlim = lim_m[b];

    const int wave = tid >> 6, lane = tid & 63, lr = lane & 15, lk = lane >> 4;
    const int p = wave >> 1, g = wave & 1;
    const unsigned short* Wp = (p == 0) ? Wk : (p == 1) ? Wq : Wv;
    const float* bp = (p == 0) ? bk : (p == 1) ? bq : bv;

    // ---- projections: stream x in 32-channel chunks, wave = (proj, half) ---
    const int cloc = tid / 12, oc = tid % 12;
    f32x4 acc[2][6];
#pragma unroll
    for (int dt = 0; dt < 2; ++dt)
#pragma unroll
        for (int nt = 0; nt < 6; ++nt) acc[dt][nt] = (f32x4)0.0f;

    uint4 v = *(const uint4*)(sg + (size_t)cloc * 9216 + oc * 8);
#pragma unroll
    for (int cc = 0; cc < 8; ++cc) {
        __syncthreads();
        {
            const unsigned short* pv = (const unsigned short*)&v;
#pragma unroll
            for (int j = 0; j < 8; ++j) {
                const int jj = (j + cloc) & 7;                 // rotate to spread banks
                xt[(oc * 8 + jj) * XT_S + cloc] = pv[jj];
            }
        }
        __syncthreads();
        if (cc < 7) v = *(const uint4*)(sg + (size_t)((cc + 1) * 32 + cloc) * 9216 + oc * 8);
        bf16x8 bfr[6];
#pragma unroll
        for (int nt = 0; nt < 6; ++nt)
            bfr[nt] = *(const bf16x8*)&xt[(nt * 16 + lr) * XT_S + lk * 8];
#pragma unroll
        for (int dt = 0; dt < 2; ++dt) {
            bf16x8 afr = *(const bf16x8*)&Wp[(size_t)(h * 64 + g * 32 + dt * 16 + lr) * 256 + cc * 32 + lk * 8];
#pragma unroll
            for (int nt = 0; nt < 6; ++nt)
                acc[dt][nt] = MFMA16(afr, bfr[nt], acc[dt][nt]);
        }
    }

    // ---- bias + store K/Q/V to LDS ----------------------------------------
#pragma unroll
    for (int dt = 0; dt < 2; ++dt) {
        const int dbase = g * 32 + dt * 16 + lk * 4;
        const float b0 = bp[h * 64 + dbase + 0], b1 = bp[h * 64 + dbase + 1];
        const float b2 = bp[h * 64 + dbase + 2], b3 = bp[h * 64 + dbase + 3];
#pragma unroll
        for (int nt = 0; nt < 6; ++nt) {
            const int n = nt * 16 + lr;
            if (p == 2) {
                Vm[(dbase + 0) * VM_S + n] = f2bf(acc[dt][nt][0] + b0);
                Vm[(dbase + 1) * VM_S + n] = f2bf(acc[dt][nt][1] + b1);
                Vm[(dbase + 2) * VM_S + n] = f2bf(acc[dt][nt][2] + b2);
                Vm[(dbase + 3) * VM_S + n] = f2bf(acc[dt][nt][3] + b3);
            } else {
                ushort4 o;
                o.x = f2bf(acc[dt][nt][0] + b0);
                o.y = f2bf(acc[dt][nt][1] + b1);
                o.z = f2bf(acc[dt][nt][2] + b2);
                o.w = f2bf(acc[dt][nt][3] + b3);
                *(ushort4*)&((p == 0 ? Kt : Qt)[n * KT_S + dbase]) = o;
            }
        }
    }
    __syncthreads();

    // ---- QK^T: wave = n-tile, all m in registers --------------------------
    f32x4 acc2[6];
#pragma unroll
    for (int mt = 0; mt < 6; ++mt) acc2[mt] = (f32x4)0.0f;
#pragma unroll
    for (int k0 = 0; k0 < 64; k0 += 32) {
        bf16x8 kf = *(const bf16x8*)&Kt[(wave * 16 + lr) * KT_S + k0 + lk * 8];
#pragma unroll
        for (int mt = 0; mt < 6; ++mt) {
            bf16x8 qf = *(const bf16x8*)&Qt[(mt * 16 + lr) * KT_S + k0 + lk * 8];
            acc2[mt] = MFMA16(kf, qf, acc2[mt]);
        }
    }

    // ---- in-register masked softmax over m (shfl across lr-group) ---------
    float lg[6][4];
#pragma unroll
    for (int mt = 0; mt < 6; ++mt) {
        const bool valid = (mt * 16 + lr) < mlim;
#pragma unroll
        for (int r2 = 0; r2 < 4; ++r2)
            lg[mt][r2] = valid ? acc2[mt][r2] * 0.125f : -3.0e38f;
    }
#pragma unroll
    for (int r2 = 0; r2 < 4; ++r2) {
        float mx = lg[0][r2];
#pragma unroll
        for (int mt = 1; mt < 6; ++mt) mx = fmaxf(mx, lg[mt][r2]);
        mx = fmaxf(mx, __shfl_xor(mx, 1));
        mx = fmaxf(mx, __shfl_xor(mx, 2));
        mx = fmaxf(mx, __shfl_xor(mx, 4));
        mx = fmaxf(mx, __shfl_xor(mx, 8));
        float sm = 0.0f;
#pragma unroll
        for (int mt = 0; mt < 6; ++mt) {
            float e = __expf(lg[mt][r2] - mx);
            lg[mt][r2] = e;
            sm += e;
        }
        sm += __shfl_xor(sm, 1);
        sm += __shfl_xor(sm, 2);
        sm += __shfl_xor(sm, 4);
        sm += __shfl_xor(sm, 8);
        const float inv = 1.0f / sm;
        const int n = wave * 16 + lk * 4 + r2;
#pragma unroll
        for (int mt = 0; mt < 6; ++mt)
            Pm[n * PM_S + mt * 16 + lr] = f2bf(lg[mt][r2] * inv);
    }
    __syncthreads();

    // ---- PV: wave = its own n-tile ----------------------------------------
    f32x4 acc3[4];
#pragma unroll
    for (int dt = 0; dt < 4; ++dt) acc3[dt] = (f32x4)0.0f;
    const int nk = (mlim + 31) >> 5;
    for (int k0i = 0; k0i < nk; ++k0i) {
        const int k0 = k0i * 32;
        bf16x8 pf = *(const bf16x8*)&Pm[(wave * 16 + lr) * PM_S + k0 + lk * 8];
#pragma unroll
        for (int dt = 0; dt < 4; ++dt) {
            bf16x8 vf = *(const bf16x8*)&Vm[(dt * 16 + lr) * VM_S + k0 + lk * 8];
            acc3[dt] = MFMA16(vf, pf, acc3[dt]);
        }
    }

    // ---- stage output tile to LDS (f32), then vectorized residual+store ---
#pragma unroll
    for (int dt = 0; dt < 4; ++dt)
#pragma unroll
        for (int r2 = 0; r2 < 4; ++r2)
            OT[(dt * 16 + lk * 4 + r2) * OT_S + wave * 16 + lr] = acc3[dt][r2];
    __syncthreads();
    for (int i = tid; i < 768; i += 384) {
        const int c = i / 12, o8 = (i % 12) * 8;
        const size_t ga = (size_t)(h * 64 + c) * 9216 + o8;
        uint4 rv = *(const uint4*)(sg + ga);
        const unsigned short* rs = (const unsigned short*)&rv;
        unsigned short ob[8];
#pragma unroll
        for (int j = 0; j < 8; ++j)
            ob[j] = f2bf(OT[c * OT_S + o8 + j] + bf2f(rs[j]));
        *(uint4*)(dg + ga) = *(const uint4*)ob;
    }
}

// ---------------------------------------------------------------------------
extern "C" void kernel_launch(void* const* d_in, const int* in_sizes, int n_in,
                              void* d_out, int out_size, void* d_ws, size_t ws_size,
                              hipStream_t stream) {
    const float* feats    = (const float*)d_in[0];
    const int*   num_rows = (const int*)d_in[1];
    const int*   num_cols = (const int*)d_in[2];

    unsigned short* bufA = (unsigned short*)d_ws;                       // 75497472 B
    unsigned short* wbuf = (unsigned short*)((char*)d_ws + 75497472);   // 1572864 B
    unsigned short* bufB = (unsigned short*)d_out;                      // scratch until final_t

    WPtrs wp;
    for (int t = 0; t < 6; ++t) wp.p[t] = (const float*)d_in[3 + 2 * t];

    (void)hipFuncSetAttribute((const void*)sa2,
                              hipFuncAttributeMaxDynamicSharedMemorySize, 68608);

    conv_w_kernel<<<768, 256, 0, stream>>>(wp, wbuf);
    conv_in_kernel<<<2048, 256, 0, stream>>>(feats, bufA, 9437184);

    unsigned short* cur = bufA;
    unsigned short* nxt = bufB;
    for (int i = 0; i < 2; ++i) {
        for (int dir = 0; dir < 2; ++dir) {
            const int tb = dir * 3;   // col: tensors 0..2, row: tensors 3..5
            const unsigned short* Wk = wbuf + (size_t)(tb + 0) * 131072 + (size_t)i * 65536;
            const unsigned short* Wq = wbuf + (size_t)(tb + 1) * 131072 + (size_t)i * 65536;
            const unsigned short* Wv = wbuf + (size_t)(tb + 2) * 131072 + (size_t)i * 65536;
            const float* bk = (const float*)d_in[4 + 2 * (tb + 0)] + i * 256;
            const float* bq = (const float*)d_in[4 + 2 * (tb + 1)] + i * 256;
            const float* bv = (const float*)d_in[4 + 2 * (tb + 2)] + i * 256;
            const int* lim_s = (dir == 0) ? num_rows : num_cols;
            const int* lim_m = (dir == 0) ? num_cols : num_rows;
            sa2<<<6144, 384, 68608, stream>>>(cur, nxt, Wk, Wq, Wv, bk, bq, bv, lim_s, lim_m);
            unsigned short* t = cur; cur = nxt; nxt = t;   // result now in `cur`
            if (!(i == 1 && dir == 1))
                transpose_ip<<<4096, 256, 0, stream>>>(cur);
        }
    }

    // after 4 stages result is back in bufA ([b][c][col][r] layout)
    final_t<<<4096, 256, 0, stream>>>(cur, (float*)d_out);
    masks_kernel<<<576, 256, 0, stream>>>(num_rows, num_cols, (float*)d_out + 37748736);
}